// Round 6
// baseline (797.333 us; speedup 1.0000x reference)
//
#include <hip/hip_runtime.h>
#include <type_traits>

#define NIN 784
#define BANKS 64
#define NLAYER 15
#define FAN 8
#define DD 10
#define NBF 640             // features per sample per layer
#define NSW 4               // samples per sample-group (per wave)
#define NSB 8               // samples per block (2 groups x 4)

// ---------------- Kernel A: input GEMM ----------------
#define BM 128
#define BN 64
#define BK 16

__global__ __launch_bounds__(256)
void input_gemm(const float* __restrict__ x, const float* __restrict__ Wi,
                const float* __restrict__ bi, float* __restrict__ acts)
{
    __shared__ float As[BK][BM + 4];
    __shared__ float Bs[BK][BN + 4];
    const int tid = threadIdx.x;
    const int tx = tid & 15, ty = tid >> 4;
    const int m0 = blockIdx.x * BM;
    const int n0 = blockIdx.y * BN;

    float acc[8][4];
#pragma unroll
    for (int i = 0; i < 8; ++i)
#pragma unroll
        for (int j = 0; j < 4; ++j) acc[i][j] = 0.f;

    for (int kb = 0; kb < NIN / BK; ++kb) {
#pragma unroll
        for (int i = 0; i < 2; ++i) {
            int flat = tid + 256 * i;
            int m = flat >> 2, kq = flat & 3;
            float4 v = *(const float4*)(x + (m0 + m) * NIN + kb * BK + kq * 4);
            As[kq*4+0][m] = v.x; As[kq*4+1][m] = v.y;
            As[kq*4+2][m] = v.z; As[kq*4+3][m] = v.w;
        }
        {
            int n = tid >> 2, kq = tid & 3;
            float4 v = *(const float4*)(Wi + (n0 + n) * NIN + kb * BK + kq * 4);
            Bs[kq*4+0][n] = v.x; Bs[kq*4+1][n] = v.y;
            Bs[kq*4+2][n] = v.z; Bs[kq*4+3][n] = v.w;
        }
        __syncthreads();
#pragma unroll
        for (int k = 0; k < BK; ++k) {
            float4 a0 = *(const float4*)(&As[k][ty*8]);
            float4 a1 = *(const float4*)(&As[k][ty*8+4]);
            float4 bb = *(const float4*)(&Bs[k][tx*4]);
            float av[8] = {a0.x,a0.y,a0.z,a0.w,a1.x,a1.y,a1.z,a1.w};
            float bv[4] = {bb.x,bb.y,bb.z,bb.w};
#pragma unroll
            for (int i = 0; i < 8; ++i)
#pragma unroll
                for (int j = 0; j < 4; ++j)
                    acc[i][j] = fmaf(av[i], bv[j], acc[i][j]);
        }
        __syncthreads();
    }
    float4 bv = *(const float4*)(bi + n0 + tx*4);
#pragma unroll
    for (int i = 0; i < 8; ++i) {
        int row = m0 + ty*8 + i;
        float4 o;
        o.x = fmaxf(acc[i][0] + bv.x, 0.f);
        o.y = fmaxf(acc[i][1] + bv.y, 0.f);
        o.z = fmaxf(acc[i][2] + bv.z, 0.f);
        o.w = fmaxf(acc[i][3] + bv.w, 0.f);
        *(float4*)(acts + row * NBF + n0 + tx*4) = o;
    }
}

__device__ __forceinline__ float f4c_rt(const float4& v, int c) {
    return c == 0 ? v.x : (c == 1 ? v.y : (c == 2 ? v.z : v.w));
}

typedef const __attribute__((address_space(1))) void gas_void;
typedef __attribute__((address_space(3))) void las_void;

__device__ __forceinline__ void gll16(const void* g, void* l) {
    __builtin_amdgcn_global_load_lds((gas_void*)g, (las_void*)l, 16, 0, 0);
}

// ---------------- Kernel T: weight pre-transpose ----------------
// chunk_t[l][k][r=0..27][bank] float4:
//   r<25 : Wd[l][bank][k] floats 4r..4r+3
//   r>=25: Wg[l][bank][k] floats 4(r-25)..+3 (zero-padded past 10)
// bias_t[l][q=0..1][bank] float4 = bg[l][bank][4q..4q+3]
#define NCH (NLAYER*FAN*28*64)   // 215040
#define NBI (NLAYER*2*64)        // 1920

__global__ __launch_bounds__(256)
void transpose_weights(const float* __restrict__ Wg, const float* __restrict__ bg,
                       const float* __restrict__ Wd,
                       float4* __restrict__ chunk_t, float4* __restrict__ bias_t)
{
    int tid = blockIdx.x * 256 + threadIdx.x;
    if (tid < NCH) {
        int b = tid & 63;
        int rk = tid >> 6;
        int r = rk % 28;
        int lk = rk / 28;           // l*8+k
        int k = lk & 7;
        int l = lk >> 3;
        float4 v;
        if (r < 25) {
            v = ((const float4*)Wd)[(((size_t)(l*64+b)*8 + k)*25) + r];
        } else {
            int q = r - 25;
            size_t base = ((size_t)(l*64+b)*8 + k)*10 + 4*q;
            float t[4];
#pragma unroll
            for (int c = 0; c < 4; ++c)
                t[c] = (4*q + c < 10) ? Wg[base + c] : 0.f;
            v = make_float4(t[0], t[1], t[2], t[3]);
        }
        chunk_t[tid] = v;
    } else if (tid < NCH + NBI) {
        int t2 = tid - NCH;
        int b = t2 & 63;
        int q = (t2 >> 6) & 1;
        int l = t2 >> 7;
        bias_t[t2] = ((const float4*)bg)[(size_t)(l*64+b)*2 + q];
    }
}

// ---------------- Kernel B (v6): register-prefetched weights, no staging ----------------
// Block = 4 waves: wave w -> g = w&1 (sample group), h = w>>1 (e-half).
// lane = bank. Weights read as coalesced 1KB global loads (L1-resident: 28KB
// chunk/CU) into a register double-buffer (wvA/wvB), prefetched one chunk
// ahead. No per-chunk barriers; only the layer-end e-half exchange syncs.
// Arithmetic order identical to v5's CT path.
__global__ __launch_bounds__(256, 2)
void routenet_v6(const float* __restrict__ acts0,
                 const float* __restrict__ x, const float* __restrict__ Wi,
                 const float* __restrict__ bi,
                 const float4* __restrict__ chunk_t, const float4* __restrict__ bias_t,
                 const float* __restrict__ Wo,
                 float* __restrict__ out, unsigned int* __restrict__ nopen_g)
{
    __shared__ float exch[2][NSW][5][64]; // [g][s][el][bank] 10240 B

    const int tid  = threadIdx.x;
    const int lane = tid & 63;
    const int w    = tid >> 6;
    const int g    = w & 1;
    const int h    = w >> 1;
    const int b0   = blockIdx.x * NSB + g * NSW;

    float a[NSW][DD];
#pragma unroll
    for (int s = 0; s < NSW; ++s) {
        const float2* p = (const float2*)(acts0 + (size_t)(b0 + s) * NBF + lane * DD);
#pragma unroll
        for (int d2 = 0; d2 < 5; ++d2) {
            float2 v = p[d2];
            a[s][d2*2]   = v.x;
            a[s][d2*2+1] = v.y;
        }
    }

    float gsum[NSW];
#pragma unroll
    for (int s = 0; s < NSW; ++s) gsum[s] = 0.f;
    unsigned int nop = 0;

    auto run = [&](auto Hc) {
        constexpr int H = Hc.value;

        float4 wvA[13], wgA[3], wvB[13], wgB[3];

        auto prefetch = [&](int l_, int k_, float4 (&wv)[13], float4 (&wg)[3]) {
            const float4* p = chunk_t + (size_t)(l_ * 8 + k_) * (28 * 64) + lane;
#pragma unroll
            for (int r = 0; r < 13; ++r) wv[r] = p[(12*H + r) * 64];
#pragma unroll
            for (int q = 0; q < 3; ++q) wg[q] = p[(25 + q) * 64];
        };

        auto compute = [&](int k, const float4 (&wv)[13], const float4 (&wg)[3],
                           float (&acc)[NSW][5], const float4& bq0, const float4& bq1) {
            float wgv[DD];
#pragma unroll
            for (int d = 0; d < DD; ++d) wgv[d] = f4c_rt(wg[d >> 2], d & 3);
            const float bias = f4c_rt((k >> 2) ? bq1 : bq0, k & 3);

            float gz[NSW];
#pragma unroll
            for (int s = 0; s < NSW; ++s) {
                float z = bias;
#pragma unroll
                for (int d = 0; d < DD; ++d) z = fmaf(a[s][d], wgv[d], z);
                float gate = fminf(fmaxf(z, 0.f), 1.f);
                if (H == 0) { gsum[s] += gate; nop += (z > 0.f) ? 1u : 0u; }
                gz[s] = gate;
            }

            const int src = (lane - k) & 63;
#pragma unroll
            for (int el = 0; el < 5; ++el) {
#pragma unroll
                for (int s = 0; s < NSW; ++s) {
                    float dot = 0.f;
#pragma unroll
                    for (int d = 0; d < DD; ++d) {
                        const int idx = (5*H + el) * 10 + d - 48*H;
                        dot = fmaf(a[s][d], f4c_rt(wv[idx >> 2], idx & 3), dot);
                    }
                    acc[s][el] += __shfl(gz[s] * dot, src, 64);
                }
            }
        };

        prefetch(0, 0, wvA, wgA);
        float4 bq0 = bias_t[lane];
        float4 bq1 = bias_t[64 + lane];

        for (int l = 0; l < NLAYER; ++l) {
            float acc[NSW][5];
#pragma unroll
            for (int s = 0; s < NSW; ++s)
#pragma unroll
                for (int el = 0; el < 5; ++el) acc[s][el] = 0.f;

            float4 bn0 = bq0, bn1 = bq1;
#pragma unroll
            for (int cc = 0; cc < 4; ++cc) {
                prefetch(l, 2*cc + 1, wvB, wgB);
                compute(2*cc, wvA, wgA, acc, bq0, bq1);
                if (cc < 3) {
                    prefetch(l, 2*cc + 2, wvA, wgA);
                } else if (l + 1 < NLAYER) {
                    prefetch(l + 1, 0, wvA, wgA);
                    bn0 = bias_t[(size_t)((l+1) * 2)     * 64 + lane];
                    bn1 = bias_t[(size_t)((l+1) * 2 + 1) * 64 + lane];
                }
                compute(2*cc + 1, wvB, wgB, acc, bq0, bq1);
            }
            bq0 = bn0; bq1 = bn1;

            // ReLU own half; exchange halves via LDS (2 phases)
            if (H == 0) {
#pragma unroll
                for (int s = 0; s < NSW; ++s)
#pragma unroll
                    for (int el = 0; el < 5; ++el)
                        a[s][el] = fmaxf(acc[s][el], 0.f);
            } else {
#pragma unroll
                for (int s = 0; s < NSW; ++s)
#pragma unroll
                    for (int el = 0; el < 5; ++el) {
                        a[s][5 + el] = fmaxf(acc[s][el], 0.f);
                        exch[g][s][el][lane] = a[s][5 + el];
                    }
            }
            asm volatile("s_waitcnt lgkmcnt(0)" ::: "memory");
            asm volatile("s_barrier" ::: "memory");

            if (H == 0) {
#pragma unroll
                for (int s = 0; s < NSW; ++s)
#pragma unroll
                    for (int el = 0; el < 5; ++el)
                        a[s][5 + el] = exch[g][s][el][lane];
                if (l + 1 < NLAYER) {   // phase B: publish d=0..4
#pragma unroll
                    for (int s = 0; s < NSW; ++s)
#pragma unroll
                        for (int el = 0; el < 5; ++el)
                            exch[g][s][el][lane] = a[s][el];
                }
            }
            if (l + 1 < NLAYER) {
                asm volatile("s_waitcnt lgkmcnt(0)" ::: "memory");
                asm volatile("s_barrier" ::: "memory");
                if (H == 1) {
#pragma unroll
                    for (int s = 0; s < NSW; ++s)
#pragma unroll
                        for (int el = 0; el < 5; ++el)
                            a[s][el] = exch[g][s][el][lane];
                }
            }
        }
    };

    if (h == 0) run(std::integral_constant<int,0>{});
    else        run(std::integral_constant<int,1>{});

    // epilogue (h=0 waves have full a)
    if (h == 0) {
        float wo[DD];
        const float2* p = (const float2*)(Wo + lane * DD);
#pragma unroll
        for (int d2 = 0; d2 < 5; ++d2) {
            float2 v = p[d2];
            wo[d2*2] = v.x; wo[d2*2+1] = v.y;
        }
#pragma unroll
        for (int s = 0; s < NSW; ++s) {
            float v = 0.f;
#pragma unroll
            for (int d = 0; d < DD; ++d) v = fmaf(a[s][d], wo[d], v);
            out[(size_t)(b0 + s) * BANKS + lane] = fmaxf(v, 0.f);
        }

#pragma unroll
        for (int s = 0; s < NSW; ++s) {
            float v = gsum[s];
#pragma unroll
            for (int off = 32; off; off >>= 1) v += __shfl_xor(v, off, 64);
            if (lane == 0)
                out[(size_t)4096 * BANKS + b0 + s] = v * (1.0f / 7680.0f);
        }
        {
            unsigned int v = nop;
#pragma unroll
            for (int off = 32; off; off >>= 1) v += __shfl_xor(v, off, 64);
            if (lane == 0) atomicAdd(nopen_g, v);
        }
    }
}

// ---------------- Fallback kernel (no-workspace path): v5-style LDS staging ----------------
__global__ __launch_bounds__(256, 2)
void routenet_v5f(const float* __restrict__ acts0,
                  const float* __restrict__ x, const float* __restrict__ Wi,
                  const float* __restrict__ bi,
                  const float* __restrict__ Wg, const float* __restrict__ bg,
                  const float* __restrict__ Wd, const float* __restrict__ Wo,
                  float* __restrict__ out, unsigned int* __restrict__ nopen_g)
{
    __shared__ float4 wdstage[2][28][64];
    __shared__ float4 biasbuf[2][2][64];
    __shared__ float  exch[2][NSW][5][64];

    const int tid  = threadIdx.x;
    const int lane = tid & 63;
    const int w    = tid >> 6;
    const int g    = w & 1;
    const int h    = w >> 1;
    const int b0   = blockIdx.x * NSB + g * NSW;

    float a[NSW][DD];

    if (acts0) {
#pragma unroll
        for (int s = 0; s < NSW; ++s) {
            const float2* p = (const float2*)(acts0 + (size_t)(b0 + s) * NBF + lane * DD);
#pragma unroll
            for (int d2 = 0; d2 < 5; ++d2) {
                float2 v = p[d2];
                a[s][d2*2]   = v.x;
                a[s][d2*2+1] = v.y;
            }
        }
    } else {
        for (int s = 0; s < NSW; ++s) {
            const float* xb = x + (size_t)(b0 + s) * NIN;
            for (int d = 0; d < DD; ++d) {
                int n = lane * DD + d;
                const float* wr = Wi + (size_t)n * NIN;
                float z = bi[n];
                for (int i = 0; i < NIN; ++i) z = fmaf(xb[i], wr[i], z);
                a[s][d] = fmaxf(z, 0.f);
            }
        }
    }

    float gsum[NSW];
#pragma unroll
    for (int s = 0; s < NSW; ++s) gsum[s] = 0.f;
    unsigned int nop = 0;

    auto stage_chunk = [&](int l, int k, int pdst) {
        const float* wd_base = Wd + (size_t)l * (BANKS*FAN*DD*DD)
                                  + (size_t)lane * (FAN*DD*DD) + k * (DD*DD);
        const float* wg_base = Wg + (size_t)l * (BANKS*FAN*DD)
                                  + lane * (FAN*DD) + ((10*k) >> 2) * 4;
#pragma unroll
        for (int j = 0; j < 7; ++j) {
            int r = w + 4 * j;
            if (r < 25) gll16(wd_base + r * 4, &wdstage[pdst][r][0]);
            else        gll16(wg_base + (r - 25) * 4, &wdstage[pdst][r][0]);
        }
    };
    auto stage_bias = [&](int l) {
        int q = w & 1;
        gll16(bg + (size_t)l * (BANKS*FAN) + lane * FAN + q * 4,
              &biasbuf[l & 1][q][0]);
    };

    stage_chunk(0, 0, 0);
    stage_bias(0);
    asm volatile("s_waitcnt vmcnt(0)" ::: "memory");
    asm volatile("s_barrier" ::: "memory");

    for (int l = 0; l < NLAYER; ++l) {
        const int lp = l & 1;
        float acc[NSW][5];
#pragma unroll
        for (int s = 0; s < NSW; ++s)
#pragma unroll
            for (int el = 0; el < 5; ++el) acc[s][el] = 0.f;

        auto chunk_body = [&](auto Hc, int k, int p) {
            constexpr int H = Hc.value;
            float4 wgq[3];
#pragma unroll
            for (int q = 0; q < 3; ++q) wgq[q] = wdstage[p][25 + q][lane];
            const float bias = f4c_rt(biasbuf[lp][(k >> 2) & 1][lane], k & 3);
            float wgv[DD];
            if ((k & 1) == 0) {
#pragma unroll
                for (int d = 0; d < DD; ++d) wgv[d] = f4c_rt(wgq[d >> 2], d & 3);
            } else {
#pragma unroll
                for (int d = 0; d < DD; ++d) wgv[d] = f4c_rt(wgq[(d+2) >> 2], (d+2) & 3);
            }

            float gz[NSW];
#pragma unroll
            for (int s = 0; s < NSW; ++s) {
                float z = bias;
#pragma unroll
                for (int d = 0; d < DD; ++d) z = fmaf(a[s][d], wgv[d], z);
                float gate = fminf(fmaxf(z, 0.f), 1.f);
                if (H == 0) { gsum[s] += gate; nop += (z > 0.f) ? 1u : 0u; }
                gz[s] = gate;
            }

            float4 wv[13];
#pragma unroll
            for (int i = 0; i < 13; ++i) wv[i] = wdstage[p][12*H + i][lane];

            const int src = (lane - k) & 63;
#pragma unroll
            for (int el = 0; el < 5; ++el) {
#pragma unroll
                for (int s = 0; s < NSW; ++s) {
                    float dot = 0.f;
#pragma unroll
                    for (int d = 0; d < DD; ++d) {
                        const int idx = (5*H + el) * 10 + d - 48*H;
                        dot = fmaf(a[s][d], f4c_rt(wv[idx >> 2], idx & 3), dot);
                    }
                    acc[s][el] += __shfl(gz[s] * dot, src, 64);
                }
            }
        };

#pragma unroll
        for (int c = 0; c < 8; ++c) {
            const int p = c & 1;
            if (c < 7) {
                stage_chunk(l, c + 1, p ^ 1);
                asm volatile("s_waitcnt vmcnt(7)" ::: "memory");
            } else if (l + 1 < NLAYER) {
                stage_chunk(l + 1, 0, p ^ 1);
                stage_bias(l + 1);
                asm volatile("s_waitcnt vmcnt(8)" ::: "memory");
            } else {
                asm volatile("s_waitcnt vmcnt(0)" ::: "memory");
            }
            asm volatile("s_barrier" ::: "memory");

            if (h == 0) chunk_body(std::integral_constant<int,0>{}, c, p);
            else        chunk_body(std::integral_constant<int,1>{}, c, p);

            if (c < 7) {
                asm volatile("s_waitcnt lgkmcnt(0)" ::: "memory");
                asm volatile("s_barrier" ::: "memory");
            }
        }

        if (h == 0) {
#pragma unroll
            for (int s = 0; s < NSW; ++s)
#pragma unroll
                for (int el = 0; el < 5; ++el)
                    a[s][el] = fmaxf(acc[s][el], 0.f);
        } else {
#pragma unroll
            for (int s = 0; s < NSW; ++s)
#pragma unroll
                for (int el = 0; el < 5; ++el) {
                    a[s][5 + el] = fmaxf(acc[s][el], 0.f);
                    exch[g][s][el][lane] = a[s][5 + el];
                }
        }
        asm volatile("s_waitcnt lgkmcnt(0)" ::: "memory");
        asm volatile("s_barrier" ::: "memory");

        if (h == 0) {
#pragma unroll
            for (int s = 0; s < NSW; ++s)
#pragma unroll
                for (int el = 0; el < 5; ++el)
                    a[s][5 + el] = exch[g][s][el][lane];
            if (l + 1 < NLAYER) {
#pragma unroll
                for (int s = 0; s < NSW; ++s)
#pragma unroll
                    for (int el = 0; el < 5; ++el)
                        exch[g][s][el][lane] = a[s][el];
            }
        }
        if (l + 1 < NLAYER) {
            asm volatile("s_waitcnt lgkmcnt(0)" ::: "memory");
            asm volatile("s_barrier" ::: "memory");
            if (h == 1) {
#pragma unroll
                for (int s = 0; s < NSW; ++s)
#pragma unroll
                    for (int el = 0; el < 5; ++el)
                        a[s][el] = exch[g][s][el][lane];
            }
        }
    }

    if (h == 0) {
        float wo[DD];
        const float2* p = (const float2*)(Wo + lane * DD);
#pragma unroll
        for (int d2 = 0; d2 < 5; ++d2) {
            float2 v = p[d2];
            wo[d2*2] = v.x; wo[d2*2+1] = v.y;
        }
#pragma unroll
        for (int s = 0; s < NSW; ++s) {
            float v = 0.f;
#pragma unroll
            for (int d = 0; d < DD; ++d) v = fmaf(a[s][d], wo[d], v);
            out[(size_t)(b0 + s) * BANKS + lane] = fmaxf(v, 0.f);
        }

#pragma unroll
        for (int s = 0; s < NSW; ++s) {
            float v = gsum[s];
#pragma unroll
            for (int off = 32; off; off >>= 1) v += __shfl_xor(v, off, 64);
            if (lane == 0)
                out[(size_t)4096 * BANKS + b0 + s] = v * (1.0f / 7680.0f);
        }
        {
            unsigned int v = nop;
#pragma unroll
            for (int off = 32; off; off >>= 1) v += __shfl_xor(v, off, 64);
            if (lane == 0) atomicAdd(nopen_g, v);
        }
    }
}

// ---------------- Kernel C: finalize scalar ----------------
__global__ void finalize_prob(const unsigned int* __restrict__ nopen,
                              float* __restrict__ out)
{
    out[4096*64 + 4096] = (float)(*nopen) / 31457280.0f;  // /(7680*4096)
}

extern "C" void kernel_launch(void* const* d_in, const int* in_sizes, int n_in,
                              void* d_out, int out_size, void* d_ws, size_t ws_size,
                              hipStream_t stream)
{
    const float* x  = (const float*)d_in[0];
    const float* Wi = (const float*)d_in[1];
    const float* bi = (const float*)d_in[2];
    const float* Wg = (const float*)d_in[3];
    const float* bg = (const float*)d_in[4];
    const float* Wd = (const float*)d_in[5];
    const float* Wo = (const float*)d_in[6];
    float* out = (float*)d_out;

    const size_t ACTS_BYTES  = (size_t)4096 * NBF * 4;          // 10485760
    const size_t CHUNK_BYTES = (size_t)NCH * 16;                //  3440640
    const size_t BIAS_BYTES  = (size_t)NBI * 16;                //    30720
    const size_t FULL_BYTES  = ACTS_BYTES + CHUNK_BYTES + BIAS_BYTES + 64;

    bool full    = ws_size >= FULL_BYTES;
    bool actonly = !full && ws_size >= ACTS_BYTES + 64;

    float* acts0 = (full || actonly) ? (float*)d_ws : nullptr;
    float4* chunk_t = full ? (float4*)((char*)d_ws + ACTS_BYTES) : nullptr;
    float4* bias_t  = full ? (float4*)((char*)d_ws + ACTS_BYTES + CHUNK_BYTES) : nullptr;
    unsigned int* nopen = full
        ? (unsigned int*)((char*)d_ws + ACTS_BYTES + CHUNK_BYTES + BIAS_BYTES)
        : (actonly ? (unsigned int*)((char*)d_ws + ACTS_BYTES)
                   : (unsigned int*)d_ws);

    hipMemsetAsync(nopen, 0, 4, stream);

    if (acts0) {
        dim3 grid(4096 / BM, NBF / BN);
        input_gemm<<<grid, 256, 0, stream>>>(x, Wi, bi, acts0);
    }
    if (full) {
        transpose_weights<<<(NCH + NBI + 255) / 256, 256, 0, stream>>>(
            Wg, bg, Wd, chunk_t, bias_t);
        routenet_v6<<<4096 / NSB, 256, 0, stream>>>(
            acts0, x, Wi, bi, chunk_t, bias_t, Wo, out, nopen);
    } else {
        routenet_v5f<<<4096 / NSB, 256, 0, stream>>>(
            acts0, x, Wi, bi, Wg, bg, Wd, Wo, out, nopen);
    }
    finalize_prob<<<1, 1, 0, stream>>>(nopen, out);
}

// Round 7
// 425.512 us; speedup vs baseline: 1.8738x; 1.8738x over previous
//
#include <hip/hip_runtime.h>

#define NIN 784
#define BANKS 64
#define NLAYER 15
#define FAN 8
#define DD 10
#define NBF 640             // features per sample per layer
#define NSW 4               // samples per sample-group (per wave)
#define NSB 8               // samples per block (2 groups x 4)

// ---------------- Kernel A: input GEMM ----------------
#define BM 128
#define BN 64
#define BK 16

__global__ __launch_bounds__(256)
void input_gemm(const float* __restrict__ x, const float* __restrict__ Wi,
                const float* __restrict__ bi, float* __restrict__ acts)
{
    __shared__ float As[BK][BM + 4];
    __shared__ float Bs[BK][BN + 4];
    const int tid = threadIdx.x;
    const int tx = tid & 15, ty = tid >> 4;
    const int m0 = blockIdx.x * BM;
    const int n0 = blockIdx.y * BN;

    float acc[8][4];
#pragma unroll
    for (int i = 0; i < 8; ++i)
#pragma unroll
        for (int j = 0; j < 4; ++j) acc[i][j] = 0.f;

    for (int kb = 0; kb < NIN / BK; ++kb) {
#pragma unroll
        for (int i = 0; i < 2; ++i) {
            int flat = tid + 256 * i;
            int m = flat >> 2, kq = flat & 3;
            float4 v = *(const float4*)(x + (m0 + m) * NIN + kb * BK + kq * 4);
            As[kq*4+0][m] = v.x; As[kq*4+1][m] = v.y;
            As[kq*4+2][m] = v.z; As[kq*4+3][m] = v.w;
        }
        {
            int n = tid >> 2, kq = tid & 3;
            float4 v = *(const float4*)(Wi + (n0 + n) * NIN + kb * BK + kq * 4);
            Bs[kq*4+0][n] = v.x; Bs[kq*4+1][n] = v.y;
            Bs[kq*4+2][n] = v.z; Bs[kq*4+3][n] = v.w;
        }
        __syncthreads();
#pragma unroll
        for (int k = 0; k < BK; ++k) {
            float4 a0 = *(const float4*)(&As[k][ty*8]);
            float4 a1 = *(const float4*)(&As[k][ty*8+4]);
            float4 bb = *(const float4*)(&Bs[k][tx*4]);
            float av[8] = {a0.x,a0.y,a0.z,a0.w,a1.x,a1.y,a1.z,a1.w};
            float bv[4] = {bb.x,bb.y,bb.z,bb.w};
#pragma unroll
            for (int i = 0; i < 8; ++i)
#pragma unroll
                for (int j = 0; j < 4; ++j)
                    acc[i][j] = fmaf(av[i], bv[j], acc[i][j]);
        }
        __syncthreads();
    }
    float4 bv = *(const float4*)(bi + n0 + tx*4);
#pragma unroll
    for (int i = 0; i < 8; ++i) {
        int row = m0 + ty*8 + i;
        float4 o;
        o.x = fmaxf(acc[i][0] + bv.x, 0.f);
        o.y = fmaxf(acc[i][1] + bv.y, 0.f);
        o.z = fmaxf(acc[i][2] + bv.z, 0.f);
        o.w = fmaxf(acc[i][3] + bv.w, 0.f);
        *(float4*)(acts + row * NBF + n0 + tx*4) = o;
    }
}

__device__ __forceinline__ float f4c_rt(const float4& v, int c) {
    return c == 0 ? v.x : (c == 1 ? v.y : (c == 2 ? v.z : v.w));
}

typedef const __attribute__((address_space(1))) void gas_void;
typedef __attribute__((address_space(3))) void las_void;

__device__ __forceinline__ void gll16(const void* g, void* l) {
    __builtin_amdgcn_global_load_lds((gas_void*)g, (las_void*)l, 16, 0, 0);
}

// ---------------- Kernel T: weight pre-transpose ----------------
// chunk_t[l][k][r=0..27][bank] float4:
//   r<25 : Wd[l][bank][k] floats 4r..4r+3
//   r>=25: Wg[l][bank][k] floats 4(r-25)..+3 (zero-padded past 10)
// bias_t[l][q=0..1][bank] float4 = bg[l][bank][4q..4q+3]
#define NCH (NLAYER*FAN*28*64)   // 215040
#define NBI (NLAYER*2*64)        // 1920

__global__ __launch_bounds__(256)
void transpose_weights(const float* __restrict__ Wg, const float* __restrict__ bg,
                       const float* __restrict__ Wd,
                       float4* __restrict__ chunk_t, float4* __restrict__ bias_t)
{
    int tid = blockIdx.x * 256 + threadIdx.x;
    if (tid < NCH) {
        int b = tid & 63;
        int rk = tid >> 6;
        int r = rk % 28;
        int lk = rk / 28;           // l*8+k
        int k = lk & 7;
        int l = lk >> 3;
        float4 v;
        if (r < 25) {
            v = ((const float4*)Wd)[(((size_t)(l*64+b)*8 + k)*25) + r];
        } else {
            int q = r - 25;
            size_t base = ((size_t)(l*64+b)*8 + k)*10 + 4*q;
            float t[4];
#pragma unroll
            for (int c = 0; c < 4; ++c)
                t[c] = (4*q + c < 10) ? Wg[base + c] : 0.f;
            v = make_float4(t[0], t[1], t[2], t[3]);
        }
        chunk_t[tid] = v;
    } else if (tid < NCH + NBI) {
        int t2 = tid - NCH;
        int b = t2 & 63;
        int q = (t2 >> 6) & 1;
        int l = t2 >> 7;
        bias_t[t2] = ((const float4*)bg)[(size_t)(l*64+b)*2 + q];
    }
}

// ---------------- v7 path: register weights from global, 1 barrier/layer ----------------
// Self-contained per-H function: all arrays local, all indices compile-time.
// ex layout: [par][ab][g][s][el][lane] floats; idx computed inline.
template<int H>
__device__ __forceinline__
void rn_path(const float* __restrict__ acts0,
             const float4* __restrict__ chunk_t,
             const float4* __restrict__ bias_t,
             const float* __restrict__ Wo,
             float* __restrict__ out,
             unsigned int* __restrict__ nopen_g,
             float* __restrict__ ex,
             const int lane, const int g, const int b0)
{
    float a[NSW][DD];
#pragma unroll
    for (int s = 0; s < NSW; ++s) {
        const float2* p = (const float2*)(acts0 + (size_t)(b0 + s) * NBF + lane * DD);
#pragma unroll
        for (int d2 = 0; d2 < 5; ++d2) {
            float2 v = p[d2];
            a[s][d2*2]   = v.x;
            a[s][d2*2+1] = v.y;
        }
    }

    float gsum[NSW];
#pragma unroll
    for (int s = 0; s < NSW; ++s) gsum[s] = 0.f;
    unsigned int nop = 0;

    for (int l = 0; l < NLAYER; ++l) {
        const float4 bq0 = bias_t[(size_t)(l*2)     * 64 + lane];
        const float4 bq1 = bias_t[(size_t)(l*2 + 1) * 64 + lane];

        float acc[NSW][5];
#pragma unroll
        for (int s = 0; s < NSW; ++s)
#pragma unroll
            for (int el = 0; el < 5; ++el) acc[s][el] = 0.f;

#pragma unroll 2
        for (int k = 0; k < FAN; ++k) {
            const float4* pb = chunk_t + ((size_t)(l*8 + k) * 28) * 64 + lane;

            // gate weights first (used first), then this half's 13 Wd rows
            float4 wgq[3];
#pragma unroll
            for (int q = 0; q < 3; ++q) wgq[q] = pb[(25 + q) * 64];
            float4 wv[13];
#pragma unroll
            for (int r = 0; r < 13; ++r) wv[r] = pb[(12*H + r) * 64];

            float wgv[DD];
#pragma unroll
            for (int d = 0; d < DD; ++d) wgv[d] = f4c_rt(wgq[d >> 2], d & 3);
            const float4 bsel = (k & 4) ? bq1 : bq0;
            const float bias = f4c_rt(bsel, k & 3);

            float gz[NSW];
#pragma unroll
            for (int s = 0; s < NSW; ++s) {
                float z = bias;
#pragma unroll
                for (int d = 0; d < DD; ++d) z = fmaf(a[s][d], wgv[d], z);
                float gate = fminf(fmaxf(z, 0.f), 1.f);
                if (H == 0) { gsum[s] += gate; nop += (z > 0.f) ? 1u : 0u; }
                gz[s] = gate;
            }

            const int src = (lane - k) & 63;
#pragma unroll
            for (int el = 0; el < 5; ++el) {
#pragma unroll
                for (int s = 0; s < NSW; ++s) {
                    float dot = 0.f;
#pragma unroll
                    for (int d = 0; d < DD; ++d) {
                        const int idx = (5*H + el) * 10 + d - 48*H;
                        dot = fmaf(a[s][d], f4c_rt(wv[idx >> 2], idx & 3), dot);
                    }
                    acc[s][el] += __shfl(gz[s] * dot, src, 64);
                }
            }
        }

        // layer-end exchange: parity ping-pong buffers, ONE barrier
        const int par = l & 1;
        // idx(par, ab, s, el) = ((((par*2+ab)*2+g)*NSW+s)*5+el)*64+lane
        if (H == 0) {
#pragma unroll
            for (int s = 0; s < NSW; ++s)
#pragma unroll
                for (int el = 0; el < 5; ++el) {
                    a[s][el] = fmaxf(acc[s][el], 0.f);
                    if (l + 1 < NLAYER)
                        ex[((((par*2+1)*2+g)*NSW+s)*5+el)*64 + lane] = a[s][el];
                }
        } else {
#pragma unroll
            for (int s = 0; s < NSW; ++s)
#pragma unroll
                for (int el = 0; el < 5; ++el) {
                    a[s][5 + el] = fmaxf(acc[s][el], 0.f);
                    ex[((((par*2+0)*2+g)*NSW+s)*5+el)*64 + lane] = a[s][5 + el];
                }
        }
        asm volatile("s_waitcnt lgkmcnt(0)" ::: "memory");
        asm volatile("s_barrier" ::: "memory");

        if (H == 0) {
#pragma unroll
            for (int s = 0; s < NSW; ++s)
#pragma unroll
                for (int el = 0; el < 5; ++el)
                    a[s][5 + el] = ex[((((par*2+0)*2+g)*NSW+s)*5+el)*64 + lane];
        } else if (l + 1 < NLAYER) {
#pragma unroll
            for (int s = 0; s < NSW; ++s)
#pragma unroll
                for (int el = 0; el < 5; ++el)
                    a[s][el] = ex[((((par*2+1)*2+g)*NSW+s)*5+el)*64 + lane];
        }
        // no trailing barrier: next write to these parity buffers is a full
        // layer (8 chunks of compute) away; parity alternation protects reuse
    }

    if (H == 0) {
        float wo[DD];
        const float2* p = (const float2*)(Wo + lane * DD);
#pragma unroll
        for (int d2 = 0; d2 < 5; ++d2) {
            float2 v = p[d2];
            wo[d2*2] = v.x; wo[d2*2+1] = v.y;
        }
#pragma unroll
        for (int s = 0; s < NSW; ++s) {
            float v = 0.f;
#pragma unroll
            for (int d = 0; d < DD; ++d) v = fmaf(a[s][d], wo[d], v);
            out[(size_t)(b0 + s) * BANKS + lane] = fmaxf(v, 0.f);
        }

#pragma unroll
        for (int s = 0; s < NSW; ++s) {
            float v = gsum[s];
#pragma unroll
            for (int off = 32; off; off >>= 1) v += __shfl_xor(v, off, 64);
            if (lane == 0)
                out[(size_t)4096 * BANKS + b0 + s] = v * (1.0f / 7680.0f);
        }
        {
            unsigned int v = nop;
#pragma unroll
            for (int off = 32; off; off >>= 1) v += __shfl_xor(v, off, 64);
            if (lane == 0) atomicAdd(nopen_g, v);
        }
    }
}

__global__ __launch_bounds__(256, 2)
void routenet_v7(const float* __restrict__ acts0,
                 const float4* __restrict__ chunk_t, const float4* __restrict__ bias_t,
                 const float* __restrict__ Wo,
                 float* __restrict__ out, unsigned int* __restrict__ nopen_g)
{
    __shared__ float ex[2*2*2*NSW*5*64];   // 40960 B [par][ab][g][s][el][lane]

    const int tid  = threadIdx.x;
    const int lane = tid & 63;
    const int w    = tid >> 6;
    const int g    = w & 1;
    const int h    = w >> 1;
    const int b0   = blockIdx.x * NSB + g * NSW;

    if (h == 0) rn_path<0>(acts0, chunk_t, bias_t, Wo, out, nopen_g, ex, lane, g, b0);
    else        rn_path<1>(acts0, chunk_t, bias_t, Wo, out, nopen_g, ex, lane, g, b0);
}

// ---------------- Fallback kernel (no-workspace path): v5-style LDS staging ----------------
__global__ __launch_bounds__(256, 2)
void routenet_v5f(const float* __restrict__ acts0,
                  const float* __restrict__ x, const float* __restrict__ Wi,
                  const float* __restrict__ bi,
                  const float* __restrict__ Wg, const float* __restrict__ bg,
                  const float* __restrict__ Wd, const float* __restrict__ Wo,
                  float* __restrict__ out, unsigned int* __restrict__ nopen_g)
{
    __shared__ float4 wdstage[2][28][64];
    __shared__ float4 biasbuf[2][2][64];
    __shared__ float  exch[2][NSW][5][64];

    const int tid  = threadIdx.x;
    const int lane = tid & 63;
    const int w    = tid >> 6;
    const int g    = w & 1;
    const int h    = w >> 1;
    const int b0   = blockIdx.x * NSB + g * NSW;

    float a[NSW][DD];

    if (acts0) {
#pragma unroll
        for (int s = 0; s < NSW; ++s) {
            const float2* p = (const float2*)(acts0 + (size_t)(b0 + s) * NBF + lane * DD);
#pragma unroll
            for (int d2 = 0; d2 < 5; ++d2) {
                float2 v = p[d2];
                a[s][d2*2]   = v.x;
                a[s][d2*2+1] = v.y;
            }
        }
    } else {
        for (int s = 0; s < NSW; ++s) {
            const float* xb = x + (size_t)(b0 + s) * NIN;
            for (int d = 0; d < DD; ++d) {
                int n = lane * DD + d;
                const float* wr = Wi + (size_t)n * NIN;
                float z = bi[n];
                for (int i = 0; i < NIN; ++i) z = fmaf(xb[i], wr[i], z);
                a[s][d] = fmaxf(z, 0.f);
            }
        }
    }

    float gsum[NSW];
#pragma unroll
    for (int s = 0; s < NSW; ++s) gsum[s] = 0.f;
    unsigned int nop = 0;

    auto stage_chunk = [&](int l, int k, int pdst) {
        const float* wd_base = Wd + (size_t)l * (BANKS*FAN*DD*DD)
                                  + (size_t)lane * (FAN*DD*DD) + k * (DD*DD);
        const float* wg_base = Wg + (size_t)l * (BANKS*FAN*DD)
                                  + lane * (FAN*DD) + ((10*k) >> 2) * 4;
#pragma unroll
        for (int j = 0; j < 7; ++j) {
            int r = w + 4 * j;
            if (r < 25) gll16(wd_base + r * 4, &wdstage[pdst][r][0]);
            else        gll16(wg_base + (r - 25) * 4, &wdstage[pdst][r][0]);
        }
    };
    auto stage_bias = [&](int l) {
        int q = w & 1;
        gll16(bg + (size_t)l * (BANKS*FAN) + lane * FAN + q * 4,
              &biasbuf[l & 1][q][0]);
    };

    stage_chunk(0, 0, 0);
    stage_bias(0);
    asm volatile("s_waitcnt vmcnt(0)" ::: "memory");
    asm volatile("s_barrier" ::: "memory");

    for (int l = 0; l < NLAYER; ++l) {
        const int lp = l & 1;
        float acc[NSW][5];
#pragma unroll
        for (int s = 0; s < NSW; ++s)
#pragma unroll
            for (int el = 0; el < 5; ++el) acc[s][el] = 0.f;

        auto chunk_body = [&](auto Hc, int k, int p) {
            constexpr int H = Hc.value;
            float4 wgq[3];
#pragma unroll
            for (int q = 0; q < 3; ++q) wgq[q] = wdstage[p][25 + q][lane];
            const float bias = f4c_rt(biasbuf[lp][(k >> 2) & 1][lane], k & 3);
            float wgv[DD];
            if ((k & 1) == 0) {
#pragma unroll
                for (int d = 0; d < DD; ++d) wgv[d] = f4c_rt(wgq[d >> 2], d & 3);
            } else {
#pragma unroll
                for (int d = 0; d < DD; ++d) wgv[d] = f4c_rt(wgq[(d+2) >> 2], (d+2) & 3);
            }

            float gz[NSW];
#pragma unroll
            for (int s = 0; s < NSW; ++s) {
                float z = bias;
#pragma unroll
                for (int d = 0; d < DD; ++d) z = fmaf(a[s][d], wgv[d], z);
                float gate = fminf(fmaxf(z, 0.f), 1.f);
                if (H == 0) { gsum[s] += gate; nop += (z > 0.f) ? 1u : 0u; }
                gz[s] = gate;
            }

            float4 wv[13];
#pragma unroll
            for (int i = 0; i < 13; ++i) wv[i] = wdstage[p][12*H + i][lane];

            const int src = (lane - k) & 63;
#pragma unroll
            for (int el = 0; el < 5; ++el) {
#pragma unroll
                for (int s = 0; s < NSW; ++s) {
                    float dot = 0.f;
#pragma unroll
                    for (int d = 0; d < DD; ++d) {
                        const int idx = (5*H + el) * 10 + d - 48*H;
                        dot = fmaf(a[s][d], f4c_rt(wv[idx >> 2], idx & 3), dot);
                    }
                    acc[s][el] += __shfl(gz[s] * dot, src, 64);
                }
            }
        };

#pragma unroll
        for (int c = 0; c < 8; ++c) {
            const int p = c & 1;
            if (c < 7) {
                stage_chunk(l, c + 1, p ^ 1);
                asm volatile("s_waitcnt vmcnt(7)" ::: "memory");
            } else if (l + 1 < NLAYER) {
                stage_chunk(l + 1, 0, p ^ 1);
                stage_bias(l + 1);
                asm volatile("s_waitcnt vmcnt(8)" ::: "memory");
            } else {
                asm volatile("s_waitcnt vmcnt(0)" ::: "memory");
            }
            asm volatile("s_barrier" ::: "memory");

            if (h == 0) chunk_body(std::integral_constant<int,0>{}, c, p);
            else        chunk_body(std::integral_constant<int,1>{}, c, p);

            if (c < 7) {
                asm volatile("s_waitcnt lgkmcnt(0)" ::: "memory");
                asm volatile("s_barrier" ::: "memory");
            }
        }

        if (h == 0) {
#pragma unroll
            for (int s = 0; s < NSW; ++s)
#pragma unroll
                for (int el = 0; el < 5; ++el)
                    a[s][el] = fmaxf(acc[s][el], 0.f);
        } else {
#pragma unroll
            for (int s = 0; s < NSW; ++s)
#pragma unroll
                for (int el = 0; el < 5; ++el) {
                    a[s][5 + el] = fmaxf(acc[s][el], 0.f);
                    exch[g][s][el][lane] = a[s][5 + el];
                }
        }
        asm volatile("s_waitcnt lgkmcnt(0)" ::: "memory");
        asm volatile("s_barrier" ::: "memory");

        if (h == 0) {
#pragma unroll
            for (int s = 0; s < NSW; ++s)
#pragma unroll
                for (int el = 0; el < 5; ++el)
                    a[s][5 + el] = exch[g][s][el][lane];
            if (l + 1 < NLAYER) {
#pragma unroll
                for (int s = 0; s < NSW; ++s)
#pragma unroll
                    for (int el = 0; el < 5; ++el)
                        exch[g][s][el][lane] = a[s][el];
            }
        }
        if (l + 1 < NLAYER) {
            asm volatile("s_waitcnt lgkmcnt(0)" ::: "memory");
            asm volatile("s_barrier" ::: "memory");
            if (h == 1) {
#pragma unroll
                for (int s = 0; s < NSW; ++s)
#pragma unroll
                    for (int el = 0; el < 5; ++el)
                        a[s][el] = exch[g][s][el][lane];
            }
        }
    }

    if (h == 0) {
        float wo[DD];
        const float2* p = (const float2*)(Wo + lane * DD);
#pragma unroll
        for (int d2 = 0; d2 < 5; ++d2) {
            float2 v = p[d2];
            wo[d2*2] = v.x; wo[d2*2+1] = v.y;
        }
#pragma unroll
        for (int s = 0; s < NSW; ++s) {
            float v = 0.f;
#pragma unroll
            for (int d = 0; d < DD; ++d) v = fmaf(a[s][d], wo[d], v);
            out[(size_t)(b0 + s) * BANKS + lane] = fmaxf(v, 0.f);
        }

#pragma unroll
        for (int s = 0; s < NSW; ++s) {
            float v = gsum[s];
#pragma unroll
            for (int off = 32; off; off >>= 1) v += __shfl_xor(v, off, 64);
            if (lane == 0)
                out[(size_t)4096 * BANKS + b0 + s] = v * (1.0f / 7680.0f);
        }
        {
            unsigned int v = nop;
#pragma unroll
            for (int off = 32; off; off >>= 1) v += __shfl_xor(v, off, 64);
            if (lane == 0) atomicAdd(nopen_g, v);
        }
    }
}

// ---------------- Kernel C: finalize scalar ----------------
__global__ void finalize_prob(const unsigned int* __restrict__ nopen,
                              float* __restrict__ out)
{
    out[4096*64 + 4096] = (float)(*nopen) / 31457280.0f;  // /(7680*4096)
}

extern "C" void kernel_launch(void* const* d_in, const int* in_sizes, int n_in,
                              void* d_out, int out_size, void* d_ws, size_t ws_size,
                              hipStream_t stream)
{
    const float* x  = (const float*)d_in[0];
    const float* Wi = (const float*)d_in[1];
    const float* bi = (const float*)d_in[2];
    const float* Wg = (const float*)d_in[3];
    const float* bg = (const float*)d_in[4];
    const float* Wd = (const float*)d_in[5];
    const float* Wo = (const float*)d_in[6];
    float* out = (float*)d_out;

    const size_t ACTS_BYTES  = (size_t)4096 * NBF * 4;          // 10485760
    const size_t CHUNK_BYTES = (size_t)NCH * 16;                //  3440640
    const size_t BIAS_BYTES  = (size_t)NBI * 16;                //    30720
    const size_t FULL_BYTES  = ACTS_BYTES + CHUNK_BYTES + BIAS_BYTES + 64;

    bool full    = ws_size >= FULL_BYTES;
    bool actonly = !full && ws_size >= ACTS_BYTES + 64;

    float* acts0 = (full || actonly) ? (float*)d_ws : nullptr;
    float4* chunk_t = full ? (float4*)((char*)d_ws + ACTS_BYTES) : nullptr;
    float4* bias_t  = full ? (float4*)((char*)d_ws + ACTS_BYTES + CHUNK_BYTES) : nullptr;
    unsigned int* nopen = full
        ? (unsigned int*)((char*)d_ws + ACTS_BYTES + CHUNK_BYTES + BIAS_BYTES)
        : (actonly ? (unsigned int*)((char*)d_ws + ACTS_BYTES)
                   : (unsigned int*)d_ws);

    hipMemsetAsync(nopen, 0, 4, stream);

    if (acts0) {
        dim3 grid(4096 / BM, NBF / BN);
        input_gemm<<<grid, 256, 0, stream>>>(x, Wi, bi, acts0);
    }
    if (full) {
        transpose_weights<<<(NCH + NBI + 255) / 256, 256, 0, stream>>>(
            Wg, bg, Wd, chunk_t, bias_t);
        routenet_v7<<<4096 / NSB, 256, 0, stream>>>(
            acts0, chunk_t, bias_t, Wo, out, nopen);
    } else {
        routenet_v5f<<<4096 / NSB, 256, 0, stream>>>(
            acts0, x, Wi, bi, Wg, bg, Wd, Wo, out, nopen);
    }
    finalize_prob<<<1, 1, 0, stream>>>(nopen, out);
}